// Round 23
// baseline (589.472 us; speedup 1.0000x reference)
//
#include <hip/hip_runtime.h>
#include <hip/hip_bf16.h>
#include <cstddef>

// ResCapsNet forward, round 23.
// - pcapsm_k staging loop re-indexed by PHYSICAL slot: ph = i%80,
//   col = (ph%10)*8 + ph/10 (inverse of the phys remap). LDS writes become
//   stride-1 across lanes (conflict-free); r22's identical conflict counter
//   proved the 5.06e6 conflicts were write-side (phys stride 10, 3-way
//   buckets), not read-side. Global loads stay row-local (160B window).
//   Bit-identical math.
// - Everything else identical to round 22 (586.5us, absmax 0.0039).

#define B_ 128
#define HW_ 80
#define PIX 6400
#define CHW 204800
#define NPRIM 1296
#define PS_ 722

typedef __attribute__((ext_vector_type(8))) short bf16x8;
typedef __attribute__((ext_vector_type(4))) float f32x4;

__device__ inline float ldH(const unsigned short* p, size_t i) {
  union { unsigned int u; float f; } c; c.u = ((unsigned int)p[i]) << 16; return c.f;
}
__device__ inline float bf16tof(unsigned short u) {
  union { unsigned int uu; float f; } c; c.uu = ((unsigned int)u) << 16; return c.f;
}
__device__ inline float lo16f(unsigned int w) {
  union { unsigned int uu; float f; } c; c.uu = w << 16; return c.f;
}
__device__ inline float hi16f(unsigned int w) {
  union { unsigned int uu; float f; } c; c.uu = w & 0xffff0000u; return c.f;
}
__device__ inline unsigned short ftobf16(float v) {
  __hip_bfloat16 b = __float2bfloat16(v);
  return *reinterpret_cast<unsigned short*>(&b);
}
__device__ inline float stRound(float* p, size_t i, float v) { p[i] = v; return v; }
__device__ inline float stRound(unsigned short* p, size_t i, float v) {
  unsigned short u = ftobf16(v); p[i] = u; return bf16tof(u);
}

// ---------------- conv1: 1->32, k3 s1 p1, + bias -> Xb (bf16); stats on rounded ------
__global__ __launch_bounds__(256) void conv1_k(const float* __restrict__ x,
                                               const float* __restrict__ w,
                                               const float* __restrict__ bias,
                                               unsigned short* __restrict__ out,
                                               float* __restrict__ partc) {
  __shared__ float sAB[4 * 64];
  int idx = blockIdx.x * 256 + threadIdx.x;      // 819200
  int b = idx / PIX, p = idx - b * PIX;
  int y = p / HW_, xx = p - y * HW_;
  const float* xb = x + (size_t)b * PIX;
  float in[3][3];
#pragma unroll
  for (int dy = 0; dy < 3; dy++) {
    int yy = y + dy - 1;
#pragma unroll
    for (int dx = 0; dx < 3; dx++) {
      int xc = xx + dx - 1;
      in[dy][dx] = (yy >= 0 && yy < HW_ && xc >= 0 && xc < HW_) ? xb[yy * HW_ + xc] : 0.f;
    }
  }
  int lane = threadIdx.x & 63, wv = threadIdx.x >> 6;
  size_t obase = (size_t)b * CHW + p;
#pragma unroll 1
  for (int co = 0; co < 32; co++) {
    float a = bias[co];
#pragma unroll
    for (int t = 0; t < 9; t++) a = fmaf(in[t / 3][t % 3], w[co * 9 + t], a);
    float ar = stRound(out, obase + (size_t)co * PIX, a);
    float r = ar, r2 = ar * ar;
#pragma unroll
    for (int off = 32; off > 0; off >>= 1) { r += __shfl_down(r, off); r2 += __shfl_down(r2, off); }
    if (lane == 0) { sAB[wv * 64 + co] = r; sAB[wv * 64 + 32 + co] = r2; }
  }
  __syncthreads();
  if (threadIdx.x < 64) {
    float s = sAB[threadIdx.x] + sAB[64 + threadIdx.x] + sAB[128 + threadIdx.x] + sAB[192 + threadIdx.x];
    partc[(size_t)blockIdx.x * 64 + threadIdx.x] = s;
  }
}

// ---------------- finalize stats: 32 blocks (one per channel) ----------------
__global__ __launch_bounds__(256) void finC_k(const float* __restrict__ partc,
                                              const float* __restrict__ g,
                                              const float* __restrict__ bb,
                                              float* __restrict__ sb) {
  __shared__ float red[256];
  int co = blockIdx.x;                           // 32
  int tid = threadIdx.x;
  int half = tid >> 7, t = tid & 127;            // half 0: sum, 1: sum^2
  const float* p = partc + (half ? (32 + co) : co);
  float s = 0.f;
  for (int j = t; j < 3200; j += 128) s += p[(size_t)j * 64];
  red[tid] = s;
  __syncthreads();
  for (int st = 64; st > 0; st >>= 1) {
    if (t < st) red[half * 128 + t] += red[half * 128 + t + st];
    __syncthreads();
  }
  if (tid == 0) {
    float sum = red[0], sum2 = red[128];
    const float inv = 1.f / 819200.f;
    float mean = sum * inv;
    float var = sum2 * inv - mean * mean;
    float sc = g[co] * rsqrtf(var + 1e-5f);
    sb[co] = sc;
    sb[32 + co] = bb[co] - mean * sc;
  }
}

// ---------------- fused: Hout = relu(bn(Xb) [+ Hb]); STATS1 via MFMA ----------------
template <bool RES, bool STATS1>
__global__ __launch_bounds__(256) void fuse_k(const unsigned short* __restrict__ X,
                                              const unsigned short* __restrict__ Hold,
                                              unsigned short* __restrict__ Hout,
                                              unsigned int* __restrict__ Xa4,
                                              const float* __restrict__ sb,
                                              const unsigned short* __restrict__ wf1,
                                              float* __restrict__ partc) {
  int tid = threadIdx.x;
  int idx = blockIdx.x * 256 + tid;              // 819200
  int b = idx / PIX, p = idx - b * PIX;
  size_t base = (size_t)b * CHW + p;
  float h[32];
#pragma unroll
  for (int ci = 0; ci < 32; ci++) {
    float v = bf16tof(X[base + (size_t)ci * PIX]);
    v = fmaf(v, sb[ci], sb[32 + ci]);
    if (RES) v += ldH(Hold, base + (size_t)ci * PIX);
    v = fmaxf(v, 0.f);
    h[ci] = stRound(Hout, base + (size_t)ci * PIX, v);
  }
  if (STATS1) {
    __shared__ unsigned int hls[16 * 260];       // plane stride 260 -> 2-way banks
    __shared__ float sAB[4 * 64];
#pragma unroll
    for (int pr = 0; pr < 16; pr++) {
      unsigned int pk = (unsigned int)ftobf16(h[2 * pr]) |
                        ((unsigned int)ftobf16(h[2 * pr + 1]) << 16);
      hls[pr * 260 + tid] = pk;
    }
    __syncthreads();

    int lane = tid & 63, wv = tid >> 6;
    int l15 = lane & 15, lg = (lane >> 4) & 3;
    int pbase = p - tid;                         // block's base pixel (uniform)

    bf16x8 ah[2], al[2];
#pragma unroll
    for (int mt = 0; mt < 2; mt++) {
      size_t ab = ((size_t)(mt * 4 + lg) * 16 + l15) * 8;
      ah[mt] = *reinterpret_cast<const bf16x8*>(wf1 + ab);
      al[mt] = *reinterpret_cast<const bf16x8*>(wf1 + 1024 + ab);
    }

    f32x4 acc[4][2];
#pragma unroll
    for (int nt = 0; nt < 4; nt++)
#pragma unroll
      for (int mt = 0; mt < 2; mt++) acc[nt][mt] = f32x4{0.f, 0.f, 0.f, 0.f};

#pragma unroll
    for (int nt = 0; nt < 4; nt++) {
      int px = wv * 64 + nt * 16 + l15;
      union { unsigned int u[4]; bf16x8 v; } bb;
      bb.u[0] = hls[(lg * 4 + 0) * 260 + px];
      bb.u[1] = hls[(lg * 4 + 1) * 260 + px];
      bb.u[2] = hls[(lg * 4 + 2) * 260 + px];
      bb.u[3] = hls[(lg * 4 + 3) * 260 + px];
#pragma unroll
      for (int mt = 0; mt < 2; mt++) {
        acc[nt][mt] = __builtin_amdgcn_mfma_f32_16x16x32_bf16(ah[mt], bb.v, acc[nt][mt], 0, 0, 0);
        acc[nt][mt] = __builtin_amdgcn_mfma_f32_16x16x32_bf16(al[mt], bb.v, acc[nt][mt], 0, 0, 0);
      }
    }

    // epilogue: pack bf16 pairs -> Xa4; stats on rounded a
    float sacc[2][4], s2acc[2][4];
#pragma unroll
    for (int mt = 0; mt < 2; mt++)
#pragma unroll
      for (int r = 0; r < 4; r++) { sacc[mt][r] = 0.f; s2acc[mt][r] = 0.f; }

#pragma unroll
    for (int nt = 0; nt < 4; nt++) {
      int px = wv * 64 + nt * 16 + l15;
      size_t xb4 = ((size_t)b * PIX + pbase + px) * 16;
#pragma unroll
      for (int mt = 0; mt < 2; mt++) {
        unsigned short u0 = ftobf16(acc[nt][mt][0]);
        unsigned short u1 = ftobf16(acc[nt][mt][1]);
        unsigned short u2 = ftobf16(acc[nt][mt][2]);
        unsigned short u3 = ftobf16(acc[nt][mt][3]);
        int pi = mt * 8 + lg * 2;
        Xa4[xb4 + pi] = (unsigned int)u0 | ((unsigned int)u1 << 16);
        Xa4[xb4 + pi + 1] = (unsigned int)u2 | ((unsigned int)u3 << 16);
        float v0 = bf16tof(u0), v1 = bf16tof(u1), v2 = bf16tof(u2), v3 = bf16tof(u3);
        sacc[mt][0] += v0; s2acc[mt][0] += v0 * v0;
        sacc[mt][1] += v1; s2acc[mt][1] += v1 * v1;
        sacc[mt][2] += v2; s2acc[mt][2] += v2 * v2;
        sacc[mt][3] += v3; s2acc[mt][3] += v3 * v3;
      }
    }
#pragma unroll
    for (int off = 1; off < 16; off <<= 1) {
#pragma unroll
      for (int mt = 0; mt < 2; mt++)
#pragma unroll
        for (int r = 0; r < 4; r++) {
          sacc[mt][r] += __shfl_xor(sacc[mt][r], off);
          s2acc[mt][r] += __shfl_xor(s2acc[mt][r], off);
        }
    }
    if (l15 == 0) {
#pragma unroll
      for (int mt = 0; mt < 2; mt++)
#pragma unroll
        for (int r = 0; r < 4; r++) {
          int co = mt * 16 + lg * 4 + r;
          sAB[wv * 64 + co] = sacc[mt][r];
          sAB[wv * 64 + 32 + co] = s2acc[mt][r];
        }
    }
    __syncthreads();
    if (tid < 64) {
      float s = sAB[tid] + sAB[64 + tid] + sAB[128 + tid] + sAB[192 + tid];
      partc[(size_t)blockIdx.x * 64 + tid] = s;
    }
  }
}

// ---------------- weight prep: pcaps A-pack + per-rb wA3 + per-rb wf1 ----------------
__global__ __launch_bounds__(256) void wprep_k(const float* __restrict__ pw,
                                               const float* __restrict__ rb3,
                                               const float* __restrict__ rb1,
                                               unsigned short* __restrict__ wpc,
                                               float* __restrict__ wp) {
  int idx = blockIdx.x * 256 + threadIdx.x;      // 1416*256 = 362496
  if (idx < 331776) {
    int j = idx & 7, co = (idx >> 3) & 127, lg = (idx >> 10) & 3, s = idx >> 12; // s<81
    int ci = lg * 8 + j;
    float w = pw[(size_t)co * 2592 + ci * 81 + s];
    unsigned short hi = ftobf16(w);
    wpc[idx] = hi;
    wpc[331776 + idx] = ftobf16(w - bf16tof(hi));
  } else if (idx < 359424) {
    int e2 = idx - 331776;                        // 27648
    int rb = e2 / 9216, e = e2 - rb * 9216;
    unsigned short* wA3 = (unsigned short*)(wp + rb * 10240);
    int j = e & 7, co = (e >> 3) & 31, g = (e >> 8) & 3, t = e >> 10;
    int ci = g * 8 + j;
    float w = rb3[rb * 9216 + (co * 32 + ci) * 9 + t];
    unsigned short hi = ftobf16(w);
    wA3[e] = hi;
    wA3[9216 + e] = ftobf16(w - bf16tof(hi));
  } else if (idx < 362496) {
    int e3 = idx - 359424;                        // 3072
    int rb = e3 / 1024, t = e3 - rb * 1024;
    unsigned short* wf1 = (unsigned short*)(wp + rb * 10240 + 9216);
    int j = t & 7, l15 = (t >> 3) & 15, lg = (t >> 7) & 3, mt = t >> 9;
    int co = mt * 16 + l15, ci = lg * 8 + j;
    float w = rb1[rb * 1024 + co * 32 + ci];
    unsigned short hi = ftobf16(w);
    wf1[t] = hi;
    wf1[1024 + t] = ftobf16(w - bf16tof(hi));
  }
}

// ---------------- conv3x3: phase-1 = coalesced Xa4 load + bn1 + relu; phase-2 MFMA ----
__global__ __launch_bounds__(256) void conv3_k(const unsigned int* __restrict__ Xa4,
                                               const float* __restrict__ sba,
                                               const unsigned short* __restrict__ wA3,
                                               unsigned short* __restrict__ X,
                                               float* __restrict__ partc) {
  __shared__ unsigned int o1s[16 * 330];          // [ci-pair][hpx], pad 330 -> 2-way banks
  __shared__ float sAB[4 * 64];
  int tile_id = blockIdx.x;                       // 25 tiles (5x5 of 16x16)
  int ty0 = (tile_id / 5) * 16, tx0 = (tile_id % 5) * 16;
  int b = blockIdx.y;
  size_t ibase = (size_t)b * CHW;

  // ---- phase 1: o1 = relu(bn1(a)) from channel-last Xa ----
  for (int px = threadIdx.x; px < 324; px += 256) {
    int iy = px / 18, ix = px - iy * 18;
    int gy = ty0 - 1 + iy, gx = tx0 - 1 + ix;
    bool inimg = (gy >= 0 && gy < HW_ && gx >= 0 && gx < HW_);
    if (inimg) {
      const uint4* src = (const uint4*)(Xa4 + ((size_t)b * PIX + gy * HW_ + gx) * 16);
      uint4 q0 = src[0], q1 = src[1], q2 = src[2], q3 = src[3];
      unsigned int raw[16] = {q0.x, q0.y, q0.z, q0.w, q1.x, q1.y, q1.z, q1.w,
                              q2.x, q2.y, q2.z, q2.w, q3.x, q3.y, q3.z, q3.w};
#pragma unroll
      for (int pr = 0; pr < 16; pr++) {
        float a0 = lo16f(raw[pr]);
        float a1 = hi16f(raw[pr]);
        // zero-padding applies AFTER bn+relu: out-of-image halo is exactly 0
        float o0 = fmaxf(fmaf(a0, sba[2 * pr], sba[32 + 2 * pr]), 0.f);
        float o1v = fmaxf(fmaf(a1, sba[2 * pr + 1], sba[32 + 2 * pr + 1]), 0.f);
        o1s[pr * 330 + px] = (unsigned int)ftobf16(o0) | ((unsigned int)ftobf16(o1v) << 16);
      }
    } else {
#pragma unroll
      for (int pr = 0; pr < 16; pr++) o1s[pr * 330 + px] = 0u;
    }
  }
  __syncthreads();

  // ---- phase 2: MFMA ----
  int lane = threadIdx.x & 63;
  int wid = threadIdx.x >> 6;
  int l15 = lane & 15, lg = lane >> 4;

  f32x4 acc8[8];                                  // unit u = s*2 + Mt; pg = wid*4+s
#pragma unroll
  for (int u = 0; u < 8; u++) acc8[u] = f32x4{0.f, 0.f, 0.f, 0.f};

#pragma unroll 1
  for (int t = 0; t < 9; t++) {
    int dy = t / 3, dx = t - dy * 3;
    int abase = ((t * 4 + lg) * 32 + l15) * 8;    // Mt=0; Mt=1 at +128
    bf16x8 ah0 = *reinterpret_cast<const bf16x8*>(wA3 + abase);
    bf16x8 ah1 = *reinterpret_cast<const bf16x8*>(wA3 + abase + 128);
    bf16x8 al0 = *reinterpret_cast<const bf16x8*>(wA3 + 9216 + abase);
    bf16x8 al1 = *reinterpret_cast<const bf16x8*>(wA3 + 9216 + abase + 128);
#pragma unroll
    for (int s = 0; s < 4; s++) {
      int hpx = (wid * 4 + s + dy) * 18 + l15 + dx;
      int wbase = lg * 4 * 330 + hpx;
      union { unsigned int u[4]; bf16x8 v; } bb;
      bb.u[0] = o1s[wbase];
      bb.u[1] = o1s[wbase + 330];
      bb.u[2] = o1s[wbase + 660];
      bb.u[3] = o1s[wbase + 990];
      acc8[s * 2 + 0] = __builtin_amdgcn_mfma_f32_16x16x32_bf16(ah0, bb.v, acc8[s * 2 + 0], 0, 0, 0);
      acc8[s * 2 + 0] = __builtin_amdgcn_mfma_f32_16x16x32_bf16(al0, bb.v, acc8[s * 2 + 0], 0, 0, 0);
      acc8[s * 2 + 1] = __builtin_amdgcn_mfma_f32_16x16x32_bf16(ah1, bb.v, acc8[s * 2 + 1], 0, 0, 0);
      acc8[s * 2 + 1] = __builtin_amdgcn_mfma_f32_16x16x32_bf16(al1, bb.v, acc8[s * 2 + 1], 0, 0, 0);
    }
  }

  // ---- store bf16 + fused bn2 stats on ROUNDED values ----
  float sacc[2][4], s2acc[2][4];
#pragma unroll
  for (int Mt = 0; Mt < 2; Mt++)
#pragma unroll
    for (int r = 0; r < 4; r++) { sacc[Mt][r] = 0.f; s2acc[Mt][r] = 0.f; }

  int gx = tx0 + l15;
#pragma unroll
  for (int s = 0; s < 4; s++) {
    int gy = ty0 + wid * 4 + s;
#pragma unroll
    for (int Mt = 0; Mt < 2; Mt++) {
#pragma unroll
      for (int r = 0; r < 4; r++) {
        unsigned short uv = ftobf16(acc8[s * 2 + Mt][r]);
        int co = Mt * 16 + lg * 4 + r;
        X[ibase + (size_t)co * PIX + gy * HW_ + gx] = uv;
        float vr = bf16tof(uv);
        sacc[Mt][r] += vr; s2acc[Mt][r] += vr * vr;
      }
    }
  }
#pragma unroll
  for (int off = 1; off < 16; off <<= 1) {
#pragma unroll
    for (int Mt = 0; Mt < 2; Mt++)
#pragma unroll
      for (int r = 0; r < 4; r++) {
        sacc[Mt][r] += __shfl_xor(sacc[Mt][r], off);
        s2acc[Mt][r] += __shfl_xor(s2acc[Mt][r], off);
      }
  }
  if (l15 == 0) {
#pragma unroll
    for (int Mt = 0; Mt < 2; Mt++)
#pragma unroll
      for (int r = 0; r < 4; r++) {
        int co = Mt * 16 + lg * 4 + r;
        sAB[wid * 64 + co] = sacc[Mt][r];
        sAB[wid * 64 + 32 + co] = s2acc[Mt][r];
      }
  }
  __syncthreads();
  if (threadIdx.x < 64) {
    float s = sAB[threadIdx.x] + sAB[64 + threadIdx.x] + sAB[128 + threadIdx.x] + sAB[192 + threadIdx.x];
    partc[((size_t)(b * 25 + tile_id)) * 64 + threadIdx.x] = s;
  }
}

// ---------------- primary caps via MFMA: per (b,oy), M=co=128, N=ox, K=2592 ----------
__global__ __launch_bounds__(256) void pcapsm_k(const unsigned short* __restrict__ Hb,
                                                const unsigned short* __restrict__ wpc,
                                                const float* __restrict__ bias,
                                                float* __restrict__ P) {
  __shared__ unsigned int hs[16 * PS_];           // 46208 B
  int oy = blockIdx.x, b = blockIdx.y;
  // stage 9 rows x 80 cols x 16 channel-pairs, iterating by PHYSICAL slot:
  // ph consecutive across lanes -> stride-1 LDS writes (conflict-free);
  // col = inverse-phys stays within one 160B H-row (still coalesced).
  for (int i = threadIdx.x; i < 11520; i += 256) {
    int pr = i / 720, rem = i - pr * 720;
    int ky = rem / 80, ph = rem - ky * 80;
    int col = (ph % 10) * 8 + (ph / 10);
    size_t src = ((size_t)(b * 32 + 2 * pr) * HW_ + oy * 8 + ky) * HW_ + col;
    unsigned int pk = (unsigned int)Hb[src] | ((unsigned int)Hb[src + PIX] << 16);
    hs[pr * PS_ + ky * 80 + ph] = pk;
  }
  __syncthreads();

  int lane = threadIdx.x & 63, wid = threadIdx.x >> 6;
  int l15 = lane & 15, lg = lane >> 4;
  int colb = (l15 < 9) ? l15 * 8 : (l15 - 9) * 8 + 4;

  f32x4 acc[2];
  acc[0] = f32x4{0.f, 0.f, 0.f, 0.f};
  acc[1] = f32x4{0.f, 0.f, 0.f, 0.f};

#pragma unroll 3
  for (int s = 0; s < 81; s++) {
    int ky = s / 9, kx = s - ky * 9;
    int c = colb + kx;
    int phys = (c & 7) * 10 + (c >> 3);
    int wb = ky * 80 + phys;
    union { unsigned int u[4]; bf16x8 v; } bb;
    bb.u[0] = hs[(lg * 4 + 0) * PS_ + wb];
    bb.u[1] = hs[(lg * 4 + 1) * PS_ + wb];
    bb.u[2] = hs[(lg * 4 + 2) * PS_ + wb];
    bb.u[3] = hs[(lg * 4 + 3) * PS_ + wb];
#pragma unroll
    for (int m = 0; m < 2; m++) {
      int mt = wid * 2 + m;
      size_t ab = ((size_t)(s * 4 + lg) * 128 + mt * 16 + l15) * 8;
      bf16x8 ahi = *reinterpret_cast<const bf16x8*>(wpc + ab);
      bf16x8 alo = *reinterpret_cast<const bf16x8*>(wpc + 331776 + ab);
      acc[m] = __builtin_amdgcn_mfma_f32_16x16x32_bf16(ahi, bb.v, acc[m], 0, 0, 0);
      acc[m] = __builtin_amdgcn_mfma_f32_16x16x32_bf16(alo, bb.v, acc[m], 0, 0, 0);
    }
  }

  int ox = l15;
  if (ox < 9) {
#pragma unroll
    for (int m = 0; m < 2; m++) {
      int mt = wid * 2 + m;
#pragma unroll
      for (int r = 0; r < 4; r++) {
        int co = mt * 16 + lg * 4 + r;
        int pp = (co >> 3) * 81 + oy * 9 + ox;
        P[((size_t)b * NPRIM + pp) * 8 + (co & 7)] = acc[m][r] + bias[co];
      }
    }
  }
}

// ---------------- u_hat (bf16) = W * P ----------------
__global__ __launch_bounds__(256) void uhat_k(const float* __restrict__ Pp,
                                              const float* __restrict__ W,
                                              unsigned short* __restrict__ UH) {
  int p = blockIdx.x;                             // 1296
  __shared__ __align__(16) float ush[1024];       // [128 b][8 k]
  for (int i = threadIdx.x; i < 1024; i += 256) {
    int b = i >> 3, k = i & 7;
    ush[i] = Pp[((size_t)b * NPRIM + p) * 8 + k];
  }
  int cdq = threadIdx.x & 31, bg = threadIdx.x >> 5;
  float4 w0[5], w1[5];
#pragma unroll
  for (int j = 0; j < 5; j++) {
    const float4* wp = (const float4*)(W + ((size_t)p * 160 + j * 32 + cdq) * 8);
    w0[j] = wp[0]; w1[j] = wp[1];
  }
  __syncthreads();
#pragma unroll 1
  for (int pass = 0; pass < 16; pass++) {
    int b = pass * 8 + bg;
    const float4* up = (const float4*)(ush + b * 8);
    float4 u0 = up[0], u1 = up[1];
#pragma unroll
    for (int j = 0; j < 5; j++) {
      float a = w0[j].x * u0.x + w0[j].y * u0.y + w0[j].z * u0.z + w0[j].w * u0.w +
                w1[j].x * u1.x + w1[j].y * u1.y + w1[j].z * u1.z + w1[j].w * u1.w;
      UH[((size_t)b * NPRIM + p) * 160 + j * 32 + cdq] = ftobf16(a);
    }
  }
}

// ---------------- round-0: s = 0.1*sum_p u_hat, inline squash -> V ----------------
__global__ __launch_bounds__(256) void sred0_k(const unsigned short* __restrict__ UH,
                                               float* __restrict__ V) {
  int c = blockIdx.x, b = blockIdx.y;
  int d = threadIdx.x & 15, pg = threadIdx.x >> 4;
  float acc = 0.f;
  for (int p = pg; p < NPRIM; p += 16)
    acc += 0.1f * bf16tof(UH[((size_t)b * NPRIM + p) * 160 + c * 16 + d]);
  __shared__ float red[256];
  red[threadIdx.x] = acc;
  __syncthreads();
  for (int st = 128; st >= 16; st >>= 1) {
    if (threadIdx.x < st) red[threadIdx.x] += red[threadIdx.x + st];
    __syncthreads();
  }
  if (threadIdx.x < 16) {
    float sv = red[threadIdx.x];
    float n2 = sv * sv;
#pragma unroll
    for (int off = 1; off < 16; off <<= 1) n2 += __shfl_xor(n2, off);
    float sc = (n2 / (1.f + n2)) / sqrtf(n2 + 1e-9f);
    V[((size_t)b * 10 + c) * 16 + threadIdx.x] = sv * sc;
  }
}

// ---------------- fused routing round (bf16 UH) ----------------
template <bool FIRST>
__global__ __launch_bounds__(256) void route_k(const unsigned short* __restrict__ UH,
                                               const float* __restrict__ V,
                                               const float* __restrict__ blogin,
                                               float* __restrict__ blogout,
                                               float* __restrict__ SPART) {
  __shared__ float cl[10 * 216];
  __shared__ float vsh[160];
  int seg = blockIdx.x, b = blockIdx.y;
  for (int i = threadIdx.x; i < 160; i += 256) vsh[i] = V[(size_t)b * 160 + i];
  __syncthreads();
  int pl = threadIdx.x;
  if (pl < 216) {
    int p = seg * 216 + pl;
    const uint4* uh4 = (const uint4*)(UH + ((size_t)b * NPRIM + p) * 160);
    float t[10];
#pragma unroll
    for (int c = 0; c < 10; c++) t[c] = 0.f;
#pragma unroll
    for (int j = 0; j < 20; j++) {                // 20 x uint4 = 160 bf16
      uint4 u = uh4[j];
      int c = j >> 1, d0 = (j & 1) * 8;
      const float* vs = vsh + c * 16 + d0;
      t[c] += lo16f(u.x) * vs[0] + hi16f(u.x) * vs[1] +
              lo16f(u.y) * vs[2] + hi16f(u.y) * vs[3] +
              lo16f(u.z) * vs[4] + hi16f(u.z) * vs[5] +
              lo16f(u.w) * vs[6] + hi16f(u.w) * vs[7];
    }
    if (!FIRST) {
      const float* bi = blogin + ((size_t)b * NPRIM + p) * 10;
#pragma unroll
      for (int c = 0; c < 10; c++) t[c] += bi[c];
    }
    float* bo = blogout + ((size_t)b * NPRIM + p) * 10;
#pragma unroll
    for (int c = 0; c < 10; c++) bo[c] = t[c];
    float mx = -3.4e38f;
#pragma unroll
    for (int c = 0; c < 10; c++) mx = fmaxf(mx, t[c]);
    float sum = 0.f;
    float e[10];
#pragma unroll
    for (int c = 0; c < 10; c++) { e[c] = __expf(t[c] - mx); sum += e[c]; }
    float inv = 1.f / sum;
#pragma unroll
    for (int c = 0; c < 10; c++) cl[c * 216 + pl] = e[c] * inv;
  }
  __syncthreads();
  if (threadIdx.x < 160) {
    int c = threadIdx.x >> 4, d = threadIdx.x & 15;
    const unsigned short* uhc = UH + ((size_t)b * NPRIM + seg * 216) * 160 + c * 16 + d;
    float s = 0.f;
#pragma unroll 4
    for (int q = 0; q < 216; q++) s += cl[c * 216 + q] * bf16tof(uhc[(size_t)q * 160]);
    SPART[((size_t)b * 6 + seg) * 160 + threadIdx.x] = s;
  }
}

// ---------------- reduce 6 partials + squash; FINAL writes v + lengths ----------------
template <bool FINAL>
__global__ __launch_bounds__(256) void squashred_k(const float* __restrict__ SPART,
                                                   float* __restrict__ V,
                                                   float* __restrict__ out) {
  int b = blockIdx.x;
  int t = threadIdx.x;
  if (t < 160) {
    float s = 0.f;
#pragma unroll
    for (int seg = 0; seg < 6; seg++) s += SPART[((size_t)b * 6 + seg) * 160 + t];
    float n2 = s * s;
#pragma unroll
    for (int off = 1; off < 16; off <<= 1) n2 += __shfl_xor(n2, off);
    float sc = (n2 / (1.f + n2)) / sqrtf(n2 + 1e-9f);
    float v = s * sc;
    if (FINAL) {
      out[(size_t)b * 160 + t] = v;
      if ((t & 15) == 0) out[20480 + b * 10 + (t >> 4)] = sqrtf(n2 * sc * sc + 1e-9f);
    } else {
      V[(size_t)b * 160 + t] = v;
    }
  }
}

extern "C" void kernel_launch(void* const* d_in, const int* in_sizes, int n_in,
                              void* d_out, int out_size, void* d_ws, size_t ws_size,
                              hipStream_t stream) {
  (void)in_sizes; (void)n_in; (void)out_size; (void)ws_size;
  const float* x        = (const float*)d_in[0];
  const float* conv1_w  = (const float*)d_in[1];
  const float* conv1_b  = (const float*)d_in[2];
  const float* bn1_g    = (const float*)d_in[3];
  const float* bn1_b    = (const float*)d_in[4];
  const float* rb_c1_w  = (const float*)d_in[5];
  const float* rb_bn1_g = (const float*)d_in[6];
  const float* rb_bn1_b = (const float*)d_in[7];
  const float* rb_c2_w  = (const float*)d_in[8];
  const float* rb_bn2_g = (const float*)d_in[9];
  const float* rb_bn2_b = (const float*)d_in[10];
  const float* pcaps_w  = (const float*)d_in[11];
  const float* pcaps_b  = (const float*)d_in[12];
  const float* W_caps   = (const float*)d_in[13];
  float* ws  = (float*)d_ws;
  float* out = (float*)d_out;

  unsigned short* Xb = (unsigned short*)ws;              // 26.2M ushorts
  unsigned short* Hb = (unsigned short*)(ws + 13107200); // 26.2M ushorts
  unsigned int* Xa4  = (unsigned int*)(ws + 26214400);   // 13.1M uints (trunk overlay)
  unsigned short* WPC = (unsigned short*)(ws + 52428800); // 663552 ush
  float* PART = ws + 52428800 + 331776;  // legacy, unused
  float* SB   = PART + 32768;            // 8 sets x 64
  float* P    = SB + 512;
  float* BLOG = P + 1327104;
  // trunk-phase overlays
  float* WP    = P;                                  // 3 x 10240 fl (wA3 + wf1 per rb)
  float* PARTC = BLOG;                               // 3200*64 fl
  // post-pcaps: UH bf16 (Xb/Hb dead after pcapsm)
  unsigned short* UH = (unsigned short*)(ws + 2654208); // 26.5M ushorts
  float* SPART = P;
  float* V     = BLOG + 1658880 + 20480;

  wprep_k<<<1416, 256, 0, stream>>>(pcaps_w, rb_c2_w, rb_c1_w, WPC, WP);
  conv1_k<<<3200, 256, 0, stream>>>(x, conv1_w, conv1_b, Xb, PARTC);
  finC_k<<<32, 256, 0, stream>>>(PARTC, bn1_g, bn1_b, SB + 0);
  fuse_k<false, true><<<3200, 256, 0, stream>>>(Xb, nullptr, Hb, Xa4, SB + 0,
                                                (unsigned short*)(WP + 0 * 10240 + 9216), PARTC);
  finC_k<<<32, 256, 0, stream>>>(PARTC, rb_bn1_g + 0, rb_bn1_b + 0, SB + 1 * 64);

  for (int i = 0; i < 3; i++) {
    int sa = 1 + 2 * i, sx = 2 + 2 * i;
    conv3_k<<<dim3(25, 128), 256, 0, stream>>>(Xa4, SB + sa * 64,
                                               (unsigned short*)(WP + i * 10240),
                                               Xb, PARTC);
    finC_k<<<32, 256, 0, stream>>>(PARTC, rb_bn2_g + i * 32, rb_bn2_b + i * 32, SB + sx * 64);
    if (i < 2) {
      fuse_k<true, true><<<3200, 256, 0, stream>>>(Xb, Hb, Hb, Xa4, SB + sx * 64,
                                                   (unsigned short*)(WP + (i + 1) * 10240 + 9216),
                                                   PARTC);
      finC_k<<<32, 256, 0, stream>>>(PARTC, rb_bn1_g + (i + 1) * 32, rb_bn1_b + (i + 1) * 32,
                                     SB + (sx + 1) * 64);
    } else {
      fuse_k<true, false><<<3200, 256, 0, stream>>>(Xb, Hb, Hb, nullptr, SB + sx * 64,
                                                    nullptr, nullptr);
    }
  }

  pcapsm_k<<<dim3(9, 128), 256, 0, stream>>>(Hb, WPC, pcaps_b, P);
  uhat_k<<<1296, 256, 0, stream>>>(P, W_caps, UH);

  // routing: r0 uniform (inline squash), then two fused rounds
  sred0_k<<<dim3(10, 128), 256, 0, stream>>>(UH, V);
  route_k<true><<<dim3(6, 128), 256, 0, stream>>>(UH, V, nullptr, BLOG, SPART);
  squashred_k<false><<<128, 256, 0, stream>>>(SPART, V, nullptr);
  route_k<false><<<dim3(6, 128), 256, 0, stream>>>(UH, V, BLOG, BLOG, SPART);
  squashred_k<true><<<128, 256, 0, stream>>>(SPART, nullptr, out);
}

// Round 24
// 587.534 us; speedup vs baseline: 1.0033x; 1.0033x over previous
//
#include <hip/hip_runtime.h>
#include <hip/hip_bf16.h>
#include <cstddef>

// ResCapsNet forward, round 24 = round 22 verbatim (measured best: 586.5us).
// r23's write-side staging permutation regressed (+3us total, pcapsm +5.7us):
// scattered global loads cost more than the conflicts saved, and conflicts
// barely moved (5.06e6 -> 4.65e6) -> residual conflicts are from the mixed
// l15<9 / l15>=9 read sub-groups, not fixable by an affine remap. Lever
// exhausted; rolling back to best.

#define B_ 128
#define HW_ 80
#define PIX 6400
#define CHW 204800
#define NPRIM 1296
#define PS_ 722

typedef __attribute__((ext_vector_type(8))) short bf16x8;
typedef __attribute__((ext_vector_type(4))) float f32x4;

__device__ inline float ldH(const unsigned short* p, size_t i) {
  union { unsigned int u; float f; } c; c.u = ((unsigned int)p[i]) << 16; return c.f;
}
__device__ inline float bf16tof(unsigned short u) {
  union { unsigned int uu; float f; } c; c.uu = ((unsigned int)u) << 16; return c.f;
}
__device__ inline float lo16f(unsigned int w) {
  union { unsigned int uu; float f; } c; c.uu = w << 16; return c.f;
}
__device__ inline float hi16f(unsigned int w) {
  union { unsigned int uu; float f; } c; c.uu = w & 0xffff0000u; return c.f;
}
__device__ inline unsigned short ftobf16(float v) {
  __hip_bfloat16 b = __float2bfloat16(v);
  return *reinterpret_cast<unsigned short*>(&b);
}
__device__ inline float stRound(float* p, size_t i, float v) { p[i] = v; return v; }
__device__ inline float stRound(unsigned short* p, size_t i, float v) {
  unsigned short u = ftobf16(v); p[i] = u; return bf16tof(u);
}

// ---------------- conv1: 1->32, k3 s1 p1, + bias -> Xb (bf16); stats on rounded ------
__global__ __launch_bounds__(256) void conv1_k(const float* __restrict__ x,
                                               const float* __restrict__ w,
                                               const float* __restrict__ bias,
                                               unsigned short* __restrict__ out,
                                               float* __restrict__ partc) {
  __shared__ float sAB[4 * 64];
  int idx = blockIdx.x * 256 + threadIdx.x;      // 819200
  int b = idx / PIX, p = idx - b * PIX;
  int y = p / HW_, xx = p - y * HW_;
  const float* xb = x + (size_t)b * PIX;
  float in[3][3];
#pragma unroll
  for (int dy = 0; dy < 3; dy++) {
    int yy = y + dy - 1;
#pragma unroll
    for (int dx = 0; dx < 3; dx++) {
      int xc = xx + dx - 1;
      in[dy][dx] = (yy >= 0 && yy < HW_ && xc >= 0 && xc < HW_) ? xb[yy * HW_ + xc] : 0.f;
    }
  }
  int lane = threadIdx.x & 63, wv = threadIdx.x >> 6;
  size_t obase = (size_t)b * CHW + p;
#pragma unroll 1
  for (int co = 0; co < 32; co++) {
    float a = bias[co];
#pragma unroll
    for (int t = 0; t < 9; t++) a = fmaf(in[t / 3][t % 3], w[co * 9 + t], a);
    float ar = stRound(out, obase + (size_t)co * PIX, a);
    float r = ar, r2 = ar * ar;
#pragma unroll
    for (int off = 32; off > 0; off >>= 1) { r += __shfl_down(r, off); r2 += __shfl_down(r2, off); }
    if (lane == 0) { sAB[wv * 64 + co] = r; sAB[wv * 64 + 32 + co] = r2; }
  }
  __syncthreads();
  if (threadIdx.x < 64) {
    float s = sAB[threadIdx.x] + sAB[64 + threadIdx.x] + sAB[128 + threadIdx.x] + sAB[192 + threadIdx.x];
    partc[(size_t)blockIdx.x * 64 + threadIdx.x] = s;
  }
}

// ---------------- finalize stats: 32 blocks (one per channel) ----------------
__global__ __launch_bounds__(256) void finC_k(const float* __restrict__ partc,
                                              const float* __restrict__ g,
                                              const float* __restrict__ bb,
                                              float* __restrict__ sb) {
  __shared__ float red[256];
  int co = blockIdx.x;                           // 32
  int tid = threadIdx.x;
  int half = tid >> 7, t = tid & 127;            // half 0: sum, 1: sum^2
  const float* p = partc + (half ? (32 + co) : co);
  float s = 0.f;
  for (int j = t; j < 3200; j += 128) s += p[(size_t)j * 64];
  red[tid] = s;
  __syncthreads();
  for (int st = 64; st > 0; st >>= 1) {
    if (t < st) red[half * 128 + t] += red[half * 128 + t + st];
    __syncthreads();
  }
  if (tid == 0) {
    float sum = red[0], sum2 = red[128];
    const float inv = 1.f / 819200.f;
    float mean = sum * inv;
    float var = sum2 * inv - mean * mean;
    float sc = g[co] * rsqrtf(var + 1e-5f);
    sb[co] = sc;
    sb[32 + co] = bb[co] - mean * sc;
  }
}

// ---------------- fused: Hout = relu(bn(Xb) [+ Hb]); STATS1 via MFMA ----------------
template <bool RES, bool STATS1>
__global__ __launch_bounds__(256) void fuse_k(const unsigned short* __restrict__ X,
                                              const unsigned short* __restrict__ Hold,
                                              unsigned short* __restrict__ Hout,
                                              unsigned int* __restrict__ Xa4,
                                              const float* __restrict__ sb,
                                              const unsigned short* __restrict__ wf1,
                                              float* __restrict__ partc) {
  int tid = threadIdx.x;
  int idx = blockIdx.x * 256 + tid;              // 819200
  int b = idx / PIX, p = idx - b * PIX;
  size_t base = (size_t)b * CHW + p;
  float h[32];
#pragma unroll
  for (int ci = 0; ci < 32; ci++) {
    float v = bf16tof(X[base + (size_t)ci * PIX]);
    v = fmaf(v, sb[ci], sb[32 + ci]);
    if (RES) v += ldH(Hold, base + (size_t)ci * PIX);
    v = fmaxf(v, 0.f);
    h[ci] = stRound(Hout, base + (size_t)ci * PIX, v);
  }
  if (STATS1) {
    __shared__ unsigned int hls[16 * 260];       // plane stride 260 -> 2-way banks
    __shared__ float sAB[4 * 64];
#pragma unroll
    for (int pr = 0; pr < 16; pr++) {
      unsigned int pk = (unsigned int)ftobf16(h[2 * pr]) |
                        ((unsigned int)ftobf16(h[2 * pr + 1]) << 16);
      hls[pr * 260 + tid] = pk;
    }
    __syncthreads();

    int lane = tid & 63, wv = tid >> 6;
    int l15 = lane & 15, lg = (lane >> 4) & 3;
    int pbase = p - tid;                         // block's base pixel (uniform)

    bf16x8 ah[2], al[2];
#pragma unroll
    for (int mt = 0; mt < 2; mt++) {
      size_t ab = ((size_t)(mt * 4 + lg) * 16 + l15) * 8;
      ah[mt] = *reinterpret_cast<const bf16x8*>(wf1 + ab);
      al[mt] = *reinterpret_cast<const bf16x8*>(wf1 + 1024 + ab);
    }

    f32x4 acc[4][2];
#pragma unroll
    for (int nt = 0; nt < 4; nt++)
#pragma unroll
      for (int mt = 0; mt < 2; mt++) acc[nt][mt] = f32x4{0.f, 0.f, 0.f, 0.f};

#pragma unroll
    for (int nt = 0; nt < 4; nt++) {
      int px = wv * 64 + nt * 16 + l15;
      union { unsigned int u[4]; bf16x8 v; } bb;
      bb.u[0] = hls[(lg * 4 + 0) * 260 + px];
      bb.u[1] = hls[(lg * 4 + 1) * 260 + px];
      bb.u[2] = hls[(lg * 4 + 2) * 260 + px];
      bb.u[3] = hls[(lg * 4 + 3) * 260 + px];
#pragma unroll
      for (int mt = 0; mt < 2; mt++) {
        acc[nt][mt] = __builtin_amdgcn_mfma_f32_16x16x32_bf16(ah[mt], bb.v, acc[nt][mt], 0, 0, 0);
        acc[nt][mt] = __builtin_amdgcn_mfma_f32_16x16x32_bf16(al[mt], bb.v, acc[nt][mt], 0, 0, 0);
      }
    }

    // epilogue: pack bf16 pairs -> Xa4; stats on rounded a
    float sacc[2][4], s2acc[2][4];
#pragma unroll
    for (int mt = 0; mt < 2; mt++)
#pragma unroll
      for (int r = 0; r < 4; r++) { sacc[mt][r] = 0.f; s2acc[mt][r] = 0.f; }

#pragma unroll
    for (int nt = 0; nt < 4; nt++) {
      int px = wv * 64 + nt * 16 + l15;
      size_t xb4 = ((size_t)b * PIX + pbase + px) * 16;
#pragma unroll
      for (int mt = 0; mt < 2; mt++) {
        unsigned short u0 = ftobf16(acc[nt][mt][0]);
        unsigned short u1 = ftobf16(acc[nt][mt][1]);
        unsigned short u2 = ftobf16(acc[nt][mt][2]);
        unsigned short u3 = ftobf16(acc[nt][mt][3]);
        int pi = mt * 8 + lg * 2;
        Xa4[xb4 + pi] = (unsigned int)u0 | ((unsigned int)u1 << 16);
        Xa4[xb4 + pi + 1] = (unsigned int)u2 | ((unsigned int)u3 << 16);
        float v0 = bf16tof(u0), v1 = bf16tof(u1), v2 = bf16tof(u2), v3 = bf16tof(u3);
        sacc[mt][0] += v0; s2acc[mt][0] += v0 * v0;
        sacc[mt][1] += v1; s2acc[mt][1] += v1 * v1;
        sacc[mt][2] += v2; s2acc[mt][2] += v2 * v2;
        sacc[mt][3] += v3; s2acc[mt][3] += v3 * v3;
      }
    }
#pragma unroll
    for (int off = 1; off < 16; off <<= 1) {
#pragma unroll
      for (int mt = 0; mt < 2; mt++)
#pragma unroll
        for (int r = 0; r < 4; r++) {
          sacc[mt][r] += __shfl_xor(sacc[mt][r], off);
          s2acc[mt][r] += __shfl_xor(s2acc[mt][r], off);
        }
    }
    if (l15 == 0) {
#pragma unroll
      for (int mt = 0; mt < 2; mt++)
#pragma unroll
        for (int r = 0; r < 4; r++) {
          int co = mt * 16 + lg * 4 + r;
          sAB[wv * 64 + co] = sacc[mt][r];
          sAB[wv * 64 + 32 + co] = s2acc[mt][r];
        }
    }
    __syncthreads();
    if (tid < 64) {
      float s = sAB[tid] + sAB[64 + tid] + sAB[128 + tid] + sAB[192 + tid];
      partc[(size_t)blockIdx.x * 64 + tid] = s;
    }
  }
}

// ---------------- weight prep: pcaps A-pack + per-rb wA3 + per-rb wf1 ----------------
__global__ __launch_bounds__(256) void wprep_k(const float* __restrict__ pw,
                                               const float* __restrict__ rb3,
                                               const float* __restrict__ rb1,
                                               unsigned short* __restrict__ wpc,
                                               float* __restrict__ wp) {
  int idx = blockIdx.x * 256 + threadIdx.x;      // 1416*256 = 362496
  if (idx < 331776) {
    int j = idx & 7, co = (idx >> 3) & 127, lg = (idx >> 10) & 3, s = idx >> 12; // s<81
    int ci = lg * 8 + j;
    float w = pw[(size_t)co * 2592 + ci * 81 + s];
    unsigned short hi = ftobf16(w);
    wpc[idx] = hi;
    wpc[331776 + idx] = ftobf16(w - bf16tof(hi));
  } else if (idx < 359424) {
    int e2 = idx - 331776;                        // 27648
    int rb = e2 / 9216, e = e2 - rb * 9216;
    unsigned short* wA3 = (unsigned short*)(wp + rb * 10240);
    int j = e & 7, co = (e >> 3) & 31, g = (e >> 8) & 3, t = e >> 10;
    int ci = g * 8 + j;
    float w = rb3[rb * 9216 + (co * 32 + ci) * 9 + t];
    unsigned short hi = ftobf16(w);
    wA3[e] = hi;
    wA3[9216 + e] = ftobf16(w - bf16tof(hi));
  } else if (idx < 362496) {
    int e3 = idx - 359424;                        // 3072
    int rb = e3 / 1024, t = e3 - rb * 1024;
    unsigned short* wf1 = (unsigned short*)(wp + rb * 10240 + 9216);
    int j = t & 7, l15 = (t >> 3) & 15, lg = (t >> 7) & 3, mt = t >> 9;
    int co = mt * 16 + l15, ci = lg * 8 + j;
    float w = rb1[rb * 1024 + co * 32 + ci];
    unsigned short hi = ftobf16(w);
    wf1[t] = hi;
    wf1[1024 + t] = ftobf16(w - bf16tof(hi));
  }
}

// ---------------- conv3x3: phase-1 = coalesced Xa4 load + bn1 + relu; phase-2 MFMA ----
__global__ __launch_bounds__(256) void conv3_k(const unsigned int* __restrict__ Xa4,
                                               const float* __restrict__ sba,
                                               const unsigned short* __restrict__ wA3,
                                               unsigned short* __restrict__ X,
                                               float* __restrict__ partc) {
  __shared__ unsigned int o1s[16 * 330];          // [ci-pair][hpx], pad 330 -> 2-way banks
  __shared__ float sAB[4 * 64];
  int tile_id = blockIdx.x;                       // 25 tiles (5x5 of 16x16)
  int ty0 = (tile_id / 5) * 16, tx0 = (tile_id % 5) * 16;
  int b = blockIdx.y;
  size_t ibase = (size_t)b * CHW;

  // ---- phase 1: o1 = relu(bn1(a)) from channel-last Xa ----
  for (int px = threadIdx.x; px < 324; px += 256) {
    int iy = px / 18, ix = px - iy * 18;
    int gy = ty0 - 1 + iy, gx = tx0 - 1 + ix;
    bool inimg = (gy >= 0 && gy < HW_ && gx >= 0 && gx < HW_);
    if (inimg) {
      const uint4* src = (const uint4*)(Xa4 + ((size_t)b * PIX + gy * HW_ + gx) * 16);
      uint4 q0 = src[0], q1 = src[1], q2 = src[2], q3 = src[3];
      unsigned int raw[16] = {q0.x, q0.y, q0.z, q0.w, q1.x, q1.y, q1.z, q1.w,
                              q2.x, q2.y, q2.z, q2.w, q3.x, q3.y, q3.z, q3.w};
#pragma unroll
      for (int pr = 0; pr < 16; pr++) {
        float a0 = lo16f(raw[pr]);
        float a1 = hi16f(raw[pr]);
        // zero-padding applies AFTER bn+relu: out-of-image halo is exactly 0
        float o0 = fmaxf(fmaf(a0, sba[2 * pr], sba[32 + 2 * pr]), 0.f);
        float o1v = fmaxf(fmaf(a1, sba[2 * pr + 1], sba[32 + 2 * pr + 1]), 0.f);
        o1s[pr * 330 + px] = (unsigned int)ftobf16(o0) | ((unsigned int)ftobf16(o1v) << 16);
      }
    } else {
#pragma unroll
      for (int pr = 0; pr < 16; pr++) o1s[pr * 330 + px] = 0u;
    }
  }
  __syncthreads();

  // ---- phase 2: MFMA ----
  int lane = threadIdx.x & 63;
  int wid = threadIdx.x >> 6;
  int l15 = lane & 15, lg = lane >> 4;

  f32x4 acc8[8];                                  // unit u = s*2 + Mt; pg = wid*4+s
#pragma unroll
  for (int u = 0; u < 8; u++) acc8[u] = f32x4{0.f, 0.f, 0.f, 0.f};

#pragma unroll 1
  for (int t = 0; t < 9; t++) {
    int dy = t / 3, dx = t - dy * 3;
    int abase = ((t * 4 + lg) * 32 + l15) * 8;    // Mt=0; Mt=1 at +128
    bf16x8 ah0 = *reinterpret_cast<const bf16x8*>(wA3 + abase);
    bf16x8 ah1 = *reinterpret_cast<const bf16x8*>(wA3 + abase + 128);
    bf16x8 al0 = *reinterpret_cast<const bf16x8*>(wA3 + 9216 + abase);
    bf16x8 al1 = *reinterpret_cast<const bf16x8*>(wA3 + 9216 + abase + 128);
#pragma unroll
    for (int s = 0; s < 4; s++) {
      int hpx = (wid * 4 + s + dy) * 18 + l15 + dx;
      int wbase = lg * 4 * 330 + hpx;
      union { unsigned int u[4]; bf16x8 v; } bb;
      bb.u[0] = o1s[wbase];
      bb.u[1] = o1s[wbase + 330];
      bb.u[2] = o1s[wbase + 660];
      bb.u[3] = o1s[wbase + 990];
      acc8[s * 2 + 0] = __builtin_amdgcn_mfma_f32_16x16x32_bf16(ah0, bb.v, acc8[s * 2 + 0], 0, 0, 0);
      acc8[s * 2 + 0] = __builtin_amdgcn_mfma_f32_16x16x32_bf16(al0, bb.v, acc8[s * 2 + 0], 0, 0, 0);
      acc8[s * 2 + 1] = __builtin_amdgcn_mfma_f32_16x16x32_bf16(ah1, bb.v, acc8[s * 2 + 1], 0, 0, 0);
      acc8[s * 2 + 1] = __builtin_amdgcn_mfma_f32_16x16x32_bf16(al1, bb.v, acc8[s * 2 + 1], 0, 0, 0);
    }
  }

  // ---- store bf16 + fused bn2 stats on ROUNDED values ----
  float sacc[2][4], s2acc[2][4];
#pragma unroll
  for (int Mt = 0; Mt < 2; Mt++)
#pragma unroll
    for (int r = 0; r < 4; r++) { sacc[Mt][r] = 0.f; s2acc[Mt][r] = 0.f; }

  int gx = tx0 + l15;
#pragma unroll
  for (int s = 0; s < 4; s++) {
    int gy = ty0 + wid * 4 + s;
#pragma unroll
    for (int Mt = 0; Mt < 2; Mt++) {
#pragma unroll
      for (int r = 0; r < 4; r++) {
        unsigned short uv = ftobf16(acc8[s * 2 + Mt][r]);
        int co = Mt * 16 + lg * 4 + r;
        X[ibase + (size_t)co * PIX + gy * HW_ + gx] = uv;
        float vr = bf16tof(uv);
        sacc[Mt][r] += vr; s2acc[Mt][r] += vr * vr;
      }
    }
  }
#pragma unroll
  for (int off = 1; off < 16; off <<= 1) {
#pragma unroll
    for (int Mt = 0; Mt < 2; Mt++)
#pragma unroll
      for (int r = 0; r < 4; r++) {
        sacc[Mt][r] += __shfl_xor(sacc[Mt][r], off);
        s2acc[Mt][r] += __shfl_xor(s2acc[Mt][r], off);
      }
  }
  if (l15 == 0) {
#pragma unroll
    for (int Mt = 0; Mt < 2; Mt++)
#pragma unroll
      for (int r = 0; r < 4; r++) {
        int co = Mt * 16 + lg * 4 + r;
        sAB[wid * 64 + co] = sacc[Mt][r];
        sAB[wid * 64 + 32 + co] = s2acc[Mt][r];
      }
  }
  __syncthreads();
  if (threadIdx.x < 64) {
    float s = sAB[threadIdx.x] + sAB[64 + threadIdx.x] + sAB[128 + threadIdx.x] + sAB[192 + threadIdx.x];
    partc[((size_t)(b * 25 + tile_id)) * 64 + threadIdx.x] = s;
  }
}

// ---------------- primary caps via MFMA: per (b,oy), M=co=128, N=ox, K=2592 ----------
__global__ __launch_bounds__(256) void pcapsm_k(const unsigned short* __restrict__ Hb,
                                                const unsigned short* __restrict__ wpc,
                                                const float* __restrict__ bias,
                                                float* __restrict__ P) {
  __shared__ unsigned int hs[16 * PS_];           // 46208 B
  int oy = blockIdx.x, b = blockIdx.y;
  // stage 9 rows x 80 cols x 16 channel-pairs; store col c at phys(c)
  for (int i = threadIdx.x; i < 11520; i += 256) {
    int pr = i / 720, rem = i - pr * 720;
    int ky = rem / 80, col = rem - ky * 80;
    size_t src = ((size_t)(b * 32 + 2 * pr) * HW_ + oy * 8 + ky) * HW_ + col;
    unsigned int pk = (unsigned int)Hb[src] | ((unsigned int)Hb[src + PIX] << 16);
    int phys = (col & 7) * 10 + (col >> 3);
    hs[pr * PS_ + ky * 80 + phys] = pk;
  }
  __syncthreads();

  int lane = threadIdx.x & 63, wid = threadIdx.x >> 6;
  int l15 = lane & 15, lg = lane >> 4;
  int colb = (l15 < 9) ? l15 * 8 : (l15 - 9) * 8 + 4;

  f32x4 acc[2];
  acc[0] = f32x4{0.f, 0.f, 0.f, 0.f};
  acc[1] = f32x4{0.f, 0.f, 0.f, 0.f};

#pragma unroll 3
  for (int s = 0; s < 81; s++) {
    int ky = s / 9, kx = s - ky * 9;
    int c = colb + kx;
    int phys = (c & 7) * 10 + (c >> 3);
    int wb = ky * 80 + phys;
    union { unsigned int u[4]; bf16x8 v; } bb;
    bb.u[0] = hs[(lg * 4 + 0) * PS_ + wb];
    bb.u[1] = hs[(lg * 4 + 1) * PS_ + wb];
    bb.u[2] = hs[(lg * 4 + 2) * PS_ + wb];
    bb.u[3] = hs[(lg * 4 + 3) * PS_ + wb];
#pragma unroll
    for (int m = 0; m < 2; m++) {
      int mt = wid * 2 + m;
      size_t ab = ((size_t)(s * 4 + lg) * 128 + mt * 16 + l15) * 8;
      bf16x8 ahi = *reinterpret_cast<const bf16x8*>(wpc + ab);
      bf16x8 alo = *reinterpret_cast<const bf16x8*>(wpc + 331776 + ab);
      acc[m] = __builtin_amdgcn_mfma_f32_16x16x32_bf16(ahi, bb.v, acc[m], 0, 0, 0);
      acc[m] = __builtin_amdgcn_mfma_f32_16x16x32_bf16(alo, bb.v, acc[m], 0, 0, 0);
    }
  }

  int ox = l15;
  if (ox < 9) {
#pragma unroll
    for (int m = 0; m < 2; m++) {
      int mt = wid * 2 + m;
#pragma unroll
      for (int r = 0; r < 4; r++) {
        int co = mt * 16 + lg * 4 + r;
        int pp = (co >> 3) * 81 + oy * 9 + ox;
        P[((size_t)b * NPRIM + pp) * 8 + (co & 7)] = acc[m][r] + bias[co];
      }
    }
  }
}

// ---------------- u_hat (bf16) = W * P ----------------
__global__ __launch_bounds__(256) void uhat_k(const float* __restrict__ Pp,
                                              const float* __restrict__ W,
                                              unsigned short* __restrict__ UH) {
  int p = blockIdx.x;                             // 1296
  __shared__ __align__(16) float ush[1024];       // [128 b][8 k]
  for (int i = threadIdx.x; i < 1024; i += 256) {
    int b = i >> 3, k = i & 7;
    ush[i] = Pp[((size_t)b * NPRIM + p) * 8 + k];
  }
  int cdq = threadIdx.x & 31, bg = threadIdx.x >> 5;
  float4 w0[5], w1[5];
#pragma unroll
  for (int j = 0; j < 5; j++) {
    const float4* wp = (const float4*)(W + ((size_t)p * 160 + j * 32 + cdq) * 8);
    w0[j] = wp[0]; w1[j] = wp[1];
  }
  __syncthreads();
#pragma unroll 1
  for (int pass = 0; pass < 16; pass++) {
    int b = pass * 8 + bg;
    const float4* up = (const float4*)(ush + b * 8);
    float4 u0 = up[0], u1 = up[1];
#pragma unroll
    for (int j = 0; j < 5; j++) {
      float a = w0[j].x * u0.x + w0[j].y * u0.y + w0[j].z * u0.z + w0[j].w * u0.w +
                w1[j].x * u1.x + w1[j].y * u1.y + w1[j].z * u1.z + w1[j].w * u1.w;
      UH[((size_t)b * NPRIM + p) * 160 + j * 32 + cdq] = ftobf16(a);
    }
  }
}

// ---------------- round-0: s = 0.1*sum_p u_hat, inline squash -> V ----------------
__global__ __launch_bounds__(256) void sred0_k(const unsigned short* __restrict__ UH,
                                               float* __restrict__ V) {
  int c = blockIdx.x, b = blockIdx.y;
  int d = threadIdx.x & 15, pg = threadIdx.x >> 4;
  float acc = 0.f;
  for (int p = pg; p < NPRIM; p += 16)
    acc += 0.1f * bf16tof(UH[((size_t)b * NPRIM + p) * 160 + c * 16 + d]);
  __shared__ float red[256];
  red[threadIdx.x] = acc;
  __syncthreads();
  for (int st = 128; st >= 16; st >>= 1) {
    if (threadIdx.x < st) red[threadIdx.x] += red[threadIdx.x + st];
    __syncthreads();
  }
  if (threadIdx.x < 16) {
    float sv = red[threadIdx.x];
    float n2 = sv * sv;
#pragma unroll
    for (int off = 1; off < 16; off <<= 1) n2 += __shfl_xor(n2, off);
    float sc = (n2 / (1.f + n2)) / sqrtf(n2 + 1e-9f);
    V[((size_t)b * 10 + c) * 16 + threadIdx.x] = sv * sc;
  }
}

// ---------------- fused routing round (bf16 UH) ----------------
template <bool FIRST>
__global__ __launch_bounds__(256) void route_k(const unsigned short* __restrict__ UH,
                                               const float* __restrict__ V,
                                               const float* __restrict__ blogin,
                                               float* __restrict__ blogout,
                                               float* __restrict__ SPART) {
  __shared__ float cl[10 * 216];
  __shared__ float vsh[160];
  int seg = blockIdx.x, b = blockIdx.y;
  for (int i = threadIdx.x; i < 160; i += 256) vsh[i] = V[(size_t)b * 160 + i];
  __syncthreads();
  int pl = threadIdx.x;
  if (pl < 216) {
    int p = seg * 216 + pl;
    const uint4* uh4 = (const uint4*)(UH + ((size_t)b * NPRIM + p) * 160);
    float t[10];
#pragma unroll
    for (int c = 0; c < 10; c++) t[c] = 0.f;
#pragma unroll
    for (int j = 0; j < 20; j++) {                // 20 x uint4 = 160 bf16
      uint4 u = uh4[j];
      int c = j >> 1, d0 = (j & 1) * 8;
      const float* vs = vsh + c * 16 + d0;
      t[c] += lo16f(u.x) * vs[0] + hi16f(u.x) * vs[1] +
              lo16f(u.y) * vs[2] + hi16f(u.y) * vs[3] +
              lo16f(u.z) * vs[4] + hi16f(u.z) * vs[5] +
              lo16f(u.w) * vs[6] + hi16f(u.w) * vs[7];
    }
    if (!FIRST) {
      const float* bi = blogin + ((size_t)b * NPRIM + p) * 10;
#pragma unroll
      for (int c = 0; c < 10; c++) t[c] += bi[c];
    }
    float* bo = blogout + ((size_t)b * NPRIM + p) * 10;
#pragma unroll
    for (int c = 0; c < 10; c++) bo[c] = t[c];
    float mx = -3.4e38f;
#pragma unroll
    for (int c = 0; c < 10; c++) mx = fmaxf(mx, t[c]);
    float sum = 0.f;
    float e[10];
#pragma unroll
    for (int c = 0; c < 10; c++) { e[c] = __expf(t[c] - mx); sum += e[c]; }
    float inv = 1.f / sum;
#pragma unroll
    for (int c = 0; c < 10; c++) cl[c * 216 + pl] = e[c] * inv;
  }
  __syncthreads();
  if (threadIdx.x < 160) {
    int c = threadIdx.x >> 4, d = threadIdx.x & 15;
    const unsigned short* uhc = UH + ((size_t)b * NPRIM + seg * 216) * 160 + c * 16 + d;
    float s = 0.f;
#pragma unroll 4
    for (int q = 0; q < 216; q++) s += cl[c * 216 + q] * bf16tof(uhc[(size_t)q * 160]);
    SPART[((size_t)b * 6 + seg) * 160 + threadIdx.x] = s;
  }
}

// ---------------- reduce 6 partials + squash; FINAL writes v + lengths ----------------
template <bool FINAL>
__global__ __launch_bounds__(256) void squashred_k(const float* __restrict__ SPART,
                                                   float* __restrict__ V,
                                                   float* __restrict__ out) {
  int b = blockIdx.x;
  int t = threadIdx.x;
  if (t < 160) {
    float s = 0.f;
#pragma unroll
    for (int seg = 0; seg < 6; seg++) s += SPART[((size_t)b * 6 + seg) * 160 + t];
    float n2 = s * s;
#pragma unroll
    for (int off = 1; off < 16; off <<= 1) n2 += __shfl_xor(n2, off);
    float sc = (n2 / (1.f + n2)) / sqrtf(n2 + 1e-9f);
    float v = s * sc;
    if (FINAL) {
      out[(size_t)b * 160 + t] = v;
      if ((t & 15) == 0) out[20480 + b * 10 + (t >> 4)] = sqrtf(n2 * sc * sc + 1e-9f);
    } else {
      V[(size_t)b * 160 + t] = v;
    }
  }
}

extern "C" void kernel_launch(void* const* d_in, const int* in_sizes, int n_in,
                              void* d_out, int out_size, void* d_ws, size_t ws_size,
                              hipStream_t stream) {
  (void)in_sizes; (void)n_in; (void)out_size; (void)ws_size;
  const float* x        = (const float*)d_in[0];
  const float* conv1_w  = (const float*)d_in[1];
  const float* conv1_b  = (const float*)d_in[2];
  const float* bn1_g    = (const float*)d_in[3];
  const float* bn1_b    = (const float*)d_in[4];
  const float* rb_c1_w  = (const float*)d_in[5];
  const float* rb_bn1_g = (const float*)d_in[6];
  const float* rb_bn1_b = (const float*)d_in[7];
  const float* rb_c2_w  = (const float*)d_in[8];
  const float* rb_bn2_g = (const float*)d_in[9];
  const float* rb_bn2_b = (const float*)d_in[10];
  const float* pcaps_w  = (const float*)d_in[11];
  const float* pcaps_b  = (const float*)d_in[12];
  const float* W_caps   = (const float*)d_in[13];
  float* ws  = (float*)d_ws;
  float* out = (float*)d_out;

  unsigned short* Xb = (unsigned short*)ws;              // 26.2M ushorts
  unsigned short* Hb = (unsigned short*)(ws + 13107200); // 26.2M ushorts
  unsigned int* Xa4  = (unsigned int*)(ws + 26214400);   // 13.1M uints (trunk overlay)
  unsigned short* WPC = (unsigned short*)(ws + 52428800); // 663552 ush
  float* PART = ws + 52428800 + 331776;  // legacy, unused
  float* SB   = PART + 32768;            // 8 sets x 64
  float* P    = SB + 512;
  float* BLOG = P + 1327104;
  // trunk-phase overlays
  float* WP    = P;                                  // 3 x 10240 fl (wA3 + wf1 per rb)
  float* PARTC = BLOG;                               // 3200*64 fl
  // post-pcaps: UH bf16 (Xb/Hb dead after pcapsm)
  unsigned short* UH = (unsigned short*)(ws + 2654208); // 26.5M ushorts
  float* SPART = P;
  float* V     = BLOG + 1658880 + 20480;

  wprep_k<<<1416, 256, 0, stream>>>(pcaps_w, rb_c2_w, rb_c1_w, WPC, WP);
  conv1_k<<<3200, 256, 0, stream>>>(x, conv1_w, conv1_b, Xb, PARTC);
  finC_k<<<32, 256, 0, stream>>>(PARTC, bn1_g, bn1_b, SB + 0);
  fuse_k<false, true><<<3200, 256, 0, stream>>>(Xb, nullptr, Hb, Xa4, SB + 0,
                                                (unsigned short*)(WP + 0 * 10240 + 9216), PARTC);
  finC_k<<<32, 256, 0, stream>>>(PARTC, rb_bn1_g + 0, rb_bn1_b + 0, SB + 1 * 64);

  for (int i = 0; i < 3; i++) {
    int sa = 1 + 2 * i, sx = 2 + 2 * i;
    conv3_k<<<dim3(25, 128), 256, 0, stream>>>(Xa4, SB + sa * 64,
                                               (unsigned short*)(WP + i * 10240),
                                               Xb, PARTC);
    finC_k<<<32, 256, 0, stream>>>(PARTC, rb_bn2_g + i * 32, rb_bn2_b + i * 32, SB + sx * 64);
    if (i < 2) {
      fuse_k<true, true><<<3200, 256, 0, stream>>>(Xb, Hb, Hb, Xa4, SB + sx * 64,
                                                   (unsigned short*)(WP + (i + 1) * 10240 + 9216),
                                                   PARTC);
      finC_k<<<32, 256, 0, stream>>>(PARTC, rb_bn1_g + (i + 1) * 32, rb_bn1_b + (i + 1) * 32,
                                     SB + (sx + 1) * 64);
    } else {
      fuse_k<true, false><<<3200, 256, 0, stream>>>(Xb, Hb, Hb, nullptr, SB + sx * 64,
                                                    nullptr, nullptr);
    }
  }

  pcapsm_k<<<dim3(9, 128), 256, 0, stream>>>(Hb, WPC, pcaps_b, P);
  uhat_k<<<1296, 256, 0, stream>>>(P, W_caps, UH);

  // routing: r0 uniform (inline squash), then two fused rounds
  sred0_k<<<dim3(10, 128), 256, 0, stream>>>(UH, V);
  route_k<true><<<dim3(6, 128), 256, 0, stream>>>(UH, V, nullptr, BLOG, SPART);
  squashred_k<false><<<128, 256, 0, stream>>>(SPART, V, nullptr);
  route_k<false><<<dim3(6, 128), 256, 0, stream>>>(UH, V, BLOG, BLOG, SPART);
  squashred_k<true><<<128, 256, 0, stream>>>(SPART, nullptr, out);
}